// Round 17
// baseline (493.483 us; speedup 1.0000x reference)
//
#include <hip/hip_runtime.h>

// ---------------------------------------------------------------------------
// 2-layer GCN. Round 17 = round 16 + exact per-(node,tile) segment bounds
// (tileofs[N][16] u16, free byproduct of csr_build's scan) so the gather gets
// round-14's tile-synchronous L2 window at round-13's per-edge cost:
// no ballot, no chunk re-reads, 13 barriers/block.
//   hs = bf16(dinv * (A@W)) row-major [N][128]
//   out[d] = relu( dinv[d] * (hs[d] + sum_{s in N(d)} hs[s]) + b )
// ---------------------------------------------------------------------------

#define NBMAX 1024          // max buckets (128 nodes each) -> N <= 131072
#define HB    512           // blocks for the scatter pass
#define CAPB  4608          // slots per bucket (mean 4096 + 8 sigma)
#define TSLOG 13            // src-tile = 8192 nodes = 2 MB of h rows

using u16 = unsigned short;
using u32 = unsigned int;
typedef __attribute__((ext_vector_type(8))) short short8;   // 8 bf16
typedef __attribute__((ext_vector_type(4))) float f32x4;

__device__ __forceinline__ u16 f2bf(float f) {
    u32 u = __float_as_uint(f);
    u += 0x7fffu + ((u >> 16) & 1u);          // round-to-nearest-even
    return (u16)(u >> 16);
}
__device__ __forceinline__ u32 pack2(float a, float b) {
    return (u32)f2bf(a) | ((u32)f2bf(b) << 16);
}
__device__ __forceinline__ float bflo(u32 u) { return __uint_as_float(u << 16); }
__device__ __forceinline__ float bfhi(u32 u) { return __uint_as_float(u & 0xffff0000u); }

// ==================== padded-bucket CSR build (no scan) ====================

__global__ __launch_bounds__(256) void k_init_bcur(u32* bcur, int NB) {
    int b = blockIdx.x * 256 + threadIdx.x;
    if (b < NB) bcur[b] = (u32)b * CAPB;
}

// Scatter edges into bucket-padded ebuf, packed u32 = (dst&127)<<17 | src.
__global__ __launch_bounds__(256) void k_scatter(const int* __restrict__ src,
                                                 const int* __restrict__ dst,
                                                 u32* __restrict__ bcur,
                                                 u32* __restrict__ ebuf,
                                                 int E, int NB) {
    __shared__ u32 hist[NBMAX];
    __shared__ u32 base[NBMAX];
    const int tid = threadIdx.x;
    for (int i = tid; i < NB; i += 256) hist[i] = 0u;
    __syncthreads();
    const int chunk = (E + gridDim.x - 1) / gridDim.x;
    const int e0 = blockIdx.x * chunk;
    const int e1 = min(E, e0 + chunk);
    for (int i = e0 + tid; i < e1; i += 256)
        atomicAdd(&hist[dst[i] >> 7], 1u);
    __syncthreads();
    for (int i = tid; i < NB; i += 256) {
        const u32 c = hist[i];
        base[i] = c ? atomicAdd(&bcur[i], c) : 0u;
    }
    __syncthreads();
    for (int i = tid; i < NB; i += 256) hist[i] = 0u;   // reuse as local cursor
    __syncthreads();
    for (int i = e0 + tid; i < e1; i += 256) {
        const int s = src[i];
        const int d = dst[i];
        const int b = d >> 7;
        const u32 loc = atomicAdd(&hist[b], 1u);
        ebuf[base[b] + loc] = ((u32)(d & 127) << 17) | (u32)s;
    }
}

// One block per bucket: per-(node, src-tile) counting sort -> rowbeg, deg,
// dinv, tile-bucketed source lists, and per-(node,tile) offsets tileofs.
__global__ __launch_bounds__(256) void k_csr_build(const u32* __restrict__ ebuf,
                                                   const u32* __restrict__ bcur,
                                                   int* __restrict__ rowbeg,
                                                   u16* __restrict__ deg16,
                                                   float* __restrict__ dinv,
                                                   int* __restrict__ csr_s,
                                                   u16* __restrict__ tileofs,
                                                   int N, int NB) {
    __shared__ u32 cnt[2048];      // [node128][tile16]
    __shared__ u32 scan[2048];
    __shared__ u32 cur[2048];
    __shared__ u32 bsum[256];
    const int tid = threadIdx.x;
    const int b = blockIdx.x;
    const int r0 = b * CAPB;
    const int r1 = (int)bcur[b];

    for (int i = tid; i < 2048; i += 256) cnt[i] = 0u;
    __syncthreads();
    for (int i = r0 + tid; i < r1; i += 256) {
        const u32 e = ebuf[i];
        const u32 key = ((e >> 17) << 4) | ((e & 0x1FFFFu) >> TSLOG);
        atomicAdd(&cnt[key], 1u);
    }
    __syncthreads();

    // exclusive scan of cnt[2048]: 8/thread serial + block scan of sums
    const int i8 = tid * 8;
    u32 pre[8];
    u32 run = 0;
#pragma unroll
    for (int j = 0; j < 8; ++j) { pre[j] = run; run += cnt[i8 + j]; }
    bsum[tid] = run;
    __syncthreads();
    for (int off = 1; off < 256; off <<= 1) {
        u32 v = bsum[tid];
        u32 add = (tid >= off) ? bsum[tid - off] : 0u;
        __syncthreads();
        bsum[tid] = v + add;
        __syncthreads();
    }
    const u32 excl = bsum[tid] - run;
#pragma unroll
    for (int j = 0; j < 8; ++j) {
        const u32 x = excl + pre[j];
        scan[i8 + j] = x;
        cur[i8 + j] = x;
    }
    __syncthreads();

    if (tid < 128) {
        const u32 beg  = scan[tid * 16];
        const u32 endv = (tid == 127) ? (u32)(r1 - r0) : scan[(tid + 1) * 16];
        const u32 dg   = endv - beg;
        const int node = b * 128 + tid;
        if (node < N) {
            rowbeg[node] = r0 + (int)beg;
            deg16[node]  = (u16)dg;
            dinv[node]   = rsqrtf((float)(dg + 1u));
            // per-tile offsets relative to rowbeg (16 u16 = 32 B, 2x uint4)
            uint4 q0, q1;
            u32 w[8];
#pragma unroll
            for (int j = 0; j < 8; ++j) {
                const u32 lo = scan[tid * 16 + 2 * j]     - beg;
                const u32 hi = scan[tid * 16 + 2 * j + 1] - beg;
                w[j] = (lo & 0xFFFFu) | (hi << 16);
            }
            q0.x = w[0]; q0.y = w[1]; q0.z = w[2]; q0.w = w[3];
            q1.x = w[4]; q1.y = w[5]; q1.z = w[6]; q1.w = w[7];
            uint4* tp = reinterpret_cast<uint4*>(tileofs + (size_t)node * 16);
            tp[0] = q0;
            tp[1] = q1;
        }
    }
    __syncthreads();

    for (int i = r0 + tid; i < r1; i += 256) {
        const u32 e = ebuf[i];
        const u32 sr = e & 0x1FFFFu;
        const u32 key = ((e >> 17) << 4) | (sr >> TSLOG);
        const u32 p = atomicAdd(&cur[key], 1u);
        csr_s[r0 + (int)p] = (int)sr;
    }
}

// ===================== W prep: transpose to [128][KP] bf16 =================
__global__ __launch_bounds__(256) void k_wprep(const float* __restrict__ W,
                                               u16* __restrict__ Wt,
                                               int K, int KP) {
    int idx = blockIdx.x * 256 + threadIdx.x;
    if (idx >= 128 * KP) return;
    int n = idx / KP, k = idx - n * KP;
    Wt[idx] = (k < K) ? f2bf(W[(size_t)k * 128 + n]) : (u16)0;
}

// ========== MFMA GEMM: H[M][128] = bf16(dinv[m] * (A @ W)) row-major =======
// 128x128 tile, 512 threads (8 waves 2x4), wave tile 64x32, BK=64.
// LDS XOR-swizzled on 16B slots. ABF=0: A fp32 [M][K]; ABF=1: A bf16 [M][128].
template <int ABF>
__global__ __launch_bounds__(512) void k_gemm_mfma(
        const void* __restrict__ Aptr,
        const u16* __restrict__ Wt,
        const float* __restrict__ dinv,
        u16* __restrict__ H, int M, int K, int KP) {
    __shared__ u16 smem[16384];        // 32 KB: As | Bs, reused by epilogue
    u16* As = smem;                    // [128][64]
    u16* Bs = smem + 128 * 64;         // [128][64]

    const int tid = threadIdx.x;
    const int row0 = blockIdx.x * 128;
    const int wid = tid >> 6;
    const int lane = tid & 63;
    const int wm = wid >> 2, wn = wid & 3;    // 2 x 4 wave grid
    const int l15 = lane & 15, lg = lane >> 4;
    const int lr7 = l15 & 7;

    const int arow = tid >> 2;                // 0..127 (row for A, col for B)
    const int achk = tid & 3;                 // 16-elem k-chunk
    const int grow = row0 + arow;
    const int ar7 = arow & 7;
    const int s0 = (achk * 2) ^ ar7;          // swizzled 16B slot indices
    const int s1 = (achk * 2 + 1) ^ ar7;

    float4 ar0, ar1, ar2, ar3;                // fp32-A staging
    uint4  au0, au1;                          // bf16-A staging
    uint4  bu0, bu1;                          // W staging

    auto load_tile = [&](int kt) {
        const int k0 = kt * 64 + achk * 16;
        if (ABF) {
            if (grow < M) {
                const u16* ap = (const u16*)Aptr + (size_t)grow * K + k0;
                au0 = *reinterpret_cast<const uint4*>(ap);
                au1 = *reinterpret_cast<const uint4*>(ap + 8);
            } else {
                au0 = make_uint4(0, 0, 0, 0);
                au1 = make_uint4(0, 0, 0, 0);
            }
        } else {
            if (grow < M && k0 < K) {       // K multiple of 16: chunks never straddle
                const float* ap = (const float*)Aptr + (size_t)grow * K + k0;
                ar0 = *reinterpret_cast<const float4*>(ap);
                ar1 = *reinterpret_cast<const float4*>(ap + 4);
                ar2 = *reinterpret_cast<const float4*>(ap + 8);
                ar3 = *reinterpret_cast<const float4*>(ap + 12);
            } else {
                ar0 = ar1 = ar2 = ar3 = make_float4(0.f, 0.f, 0.f, 0.f);
            }
        }
        const u16* wp = Wt + (size_t)arow * KP + k0;    // arow doubles as bcol
        bu0 = *reinterpret_cast<const uint4*>(wp);
        bu1 = *reinterpret_cast<const uint4*>(wp + 8);
    };

    auto store_tile = [&]() {
        uint4 w0, w1;
        if (ABF) {
            w0 = au0; w1 = au1;
        } else {
            w0.x = pack2(ar0.x, ar0.y); w0.y = pack2(ar0.z, ar0.w);
            w0.z = pack2(ar1.x, ar1.y); w0.w = pack2(ar1.z, ar1.w);
            w1.x = pack2(ar2.x, ar2.y); w1.y = pack2(ar2.z, ar2.w);
            w1.z = pack2(ar3.x, ar3.y); w1.w = pack2(ar3.z, ar3.w);
        }
        u16* ad = As + arow * 64;
        *reinterpret_cast<uint4*>(ad + s0 * 8) = w0;
        *reinterpret_cast<uint4*>(ad + s1 * 8) = w1;
        u16* bd = Bs + arow * 64;
        *reinterpret_cast<uint4*>(bd + s0 * 8) = bu0;
        *reinterpret_cast<uint4*>(bd + s1 * 8) = bu1;
    };

    f32x4 acc[4][2];
#pragma unroll
    for (int i = 0; i < 4; ++i)
#pragma unroll
        for (int j = 0; j < 2; ++j)
            acc[i][j] = (f32x4){0.f, 0.f, 0.f, 0.f};

    const int NT = KP >> 6;
    load_tile(0);
    for (int kt = 0; kt < NT; ++kt) {
        __syncthreads();
        store_tile();
        __syncthreads();
        if (kt + 1 < NT) load_tile(kt + 1);   // reg prefetch under MFMA
#pragma unroll
        for (int sub = 0; sub < 2; ++sub) {
            const int slot = ((sub * 4 + lg) ^ lr7) * 8;
            short8 af[4], bf[2];
#pragma unroll
            for (int i = 0; i < 4; ++i)
                af[i] = *reinterpret_cast<const short8*>(
                    As + (wm * 64 + i * 16 + l15) * 64 + slot);
#pragma unroll
            for (int j = 0; j < 2; ++j)
                bf[j] = *reinterpret_cast<const short8*>(
                    Bs + (wn * 32 + j * 16 + l15) * 64 + slot);
#pragma unroll
            for (int i = 0; i < 4; ++i)
#pragma unroll
                for (int j = 0; j < 2; ++j)
                    acc[i][j] = __builtin_amdgcn_mfma_f32_16x16x32_bf16(
                        af[i], bf[j], acc[i][j], 0, 0, 0);
        }
    }

    // Epilogue: dinv*acc -> bf16 staged in LDS (CSTR=136) -> 32B row stores.
    const int CSTR = 136;
    __syncthreads();
#pragma unroll
    for (int half = 0; half < 2; ++half) {
        if (wm == half) {
#pragma unroll
            for (int i = 0; i < 4; ++i)
#pragma unroll
                for (int r = 0; r < 4; ++r) {
                    const int gr = row0 + half * 64 + i * 16 + lg * 4 + r;
                    const float dv = (gr < M) ? dinv[gr] : 0.f;
#pragma unroll
                    for (int j = 0; j < 2; ++j)
                        smem[(i * 16 + lg * 4 + r) * CSTR + wn * 32 + j * 16 + l15] =
                            f2bf(acc[i][j][r] * dv);
                }
        }
        __syncthreads();
        {
            const int rr = tid >> 3;            // 0..63
            const int cc = (tid & 7) * 16;      // 0..112
            const int gr = row0 + half * 64 + rr;
            if (gr < M) {
                const u16* cp = smem + rr * CSTR + cc;
                uint4 q0 = *reinterpret_cast<const uint4*>(cp);
                uint4 q1 = *reinterpret_cast<const uint4*>(cp + 8);
                uint4* hp = reinterpret_cast<uint4*>(H + (size_t)gr * 128 + cc);
                hp[0] = q0; hp[1] = q1;
            }
        }
        __syncthreads();
    }
}

// ========================= gather (pull aggregation) =======================
// 16 nodes/block, 16 lanes/node, 8 bf16 cols (16B) per lane. Outer loop over
// src tiles with exact segment bounds from tileofs; one barrier per tile
// keeps all co-resident blocks in the same 2 MB h window.
template <int OUTBF>
__global__ __launch_bounds__(256) void k_gather(const int* __restrict__ rowbeg,
                                                const u16* __restrict__ deg16,
                                                const float* __restrict__ dinv,
                                                const int* __restrict__ csr_s,
                                                const u16* __restrict__ tileofs,
                                                const u16* __restrict__ H,
                                                const float* __restrict__ bias,
                                                void* __restrict__ outp,
                                                int N, int NT) {
    const int t = threadIdx.x;
    const int node = blockIdx.x * 16 + (t >> 4);
    const bool act = node < N;
    const int lane = t & 15;
    const int c8 = lane * 8;

    float acc0 = 0.f, acc1 = 0.f, acc2 = 0.f, acc3 = 0.f;
    float acc4 = 0.f, acc5 = 0.f, acc6 = 0.f, acc7 = 0.f;
    int beg = 0, dg = 0;
    const u16* tofs = tileofs;
    if (act) {
        const uint4 hv = *reinterpret_cast<const uint4*>(H + (size_t)node * 128 + c8);
        acc0 = bflo(hv.x); acc1 = bfhi(hv.x);
        acc2 = bflo(hv.y); acc3 = bfhi(hv.y);
        acc4 = bflo(hv.z); acc5 = bfhi(hv.z);
        acc6 = bflo(hv.w); acc7 = bfhi(hv.w);
        beg = rowbeg[node];
        dg  = (int)deg16[node];
        tofs = tileofs + (size_t)node * 16;
    }

    for (int tt = 0; tt < NT; ++tt) {
        if (act) {
            const int o0 = (int)tofs[tt];
            const int o1 = (tt + 1 >= NT) ? dg : (int)tofs[tt + 1];
            const int send = beg + o1;
            for (int r = beg + o0; r < send; r += 16) {
                const int cntc = min(16, send - r);
                int sv = (lane < cntc) ? csr_s[r + lane] : 0;
                for (int j = 0; j < cntc; ++j) {
                    const int s = __shfl(sv, j, 16);
                    const uint4 x = *reinterpret_cast<const uint4*>(H + (size_t)s * 128 + c8);
                    acc0 += bflo(x.x); acc1 += bfhi(x.x);
                    acc2 += bflo(x.y); acc3 += bfhi(x.y);
                    acc4 += bflo(x.z); acc5 += bfhi(x.z);
                    acc6 += bflo(x.w); acc7 += bfhi(x.w);
                }
            }
        }
        __syncthreads();        // hold all groups in the same src tile window
    }

    if (!act) return;
    const float dv = dinv[node];
    const float4 b0 = *reinterpret_cast<const float4*>(bias + c8);
    const float4 b1 = *reinterpret_cast<const float4*>(bias + c8 + 4);
    const float r0 = fmaxf(fmaf(acc0, dv, b0.x), 0.f);
    const float r1 = fmaxf(fmaf(acc1, dv, b0.y), 0.f);
    const float r2 = fmaxf(fmaf(acc2, dv, b0.z), 0.f);
    const float r3 = fmaxf(fmaf(acc3, dv, b0.w), 0.f);
    const float r4 = fmaxf(fmaf(acc4, dv, b1.x), 0.f);
    const float r5 = fmaxf(fmaf(acc5, dv, b1.y), 0.f);
    const float r6 = fmaxf(fmaf(acc6, dv, b1.z), 0.f);
    const float r7 = fmaxf(fmaf(acc7, dv, b1.w), 0.f);

    if (OUTBF) {
        uint4 q;
        q.x = pack2(r0, r1); q.y = pack2(r2, r3);
        q.z = pack2(r4, r5); q.w = pack2(r6, r7);
        u16* op = (u16*)outp + (size_t)node * 128 + c8;
        *reinterpret_cast<uint4*>(op) = q;
    } else {
        float* op = (float*)outp + (size_t)node * 128 + c8;
        *reinterpret_cast<float4*>(op)     = make_float4(r0, r1, r2, r3);
        *reinterpret_cast<float4*>(op + 4) = make_float4(r4, r5, r6, r7);
    }
}

// ===========================================================================

extern "C" void kernel_launch(void* const* d_in, const int* in_sizes, int n_in,
                              void* d_out, int out_size, void* d_ws, size_t ws_size,
                              hipStream_t stream) {
    const float* x  = (const float*)d_in[0];
    const int*   ei = (const int*)d_in[1];
    const float* W1 = (const float*)d_in[3];
    const float* b1 = (const float*)d_in[4];
    const float* W2 = (const float*)d_in[5];
    const float* b2 = (const float*)d_in[6];
    float* out = (float*)d_out;

    const int N = in_sizes[0] / 400;
    const int E = in_sizes[1] / 2;
    const int* src = ei;
    const int* dst = ei + E;
    const int NB = (N + 127) >> 7;
    const int NT = (N + (1 << TSLOG) - 1) >> TSLOG;   // src tiles (13 @ N=100k)
    const int KP1 = 448;                // 400 padded to 7*64
    const int KP2 = 128;

    char* ws = (char*)d_ws;
    size_t off = 0;
    auto alloc = [&](size_t bytes) {
        void* p = ws + off;
        off = (off + bytes + 255) & ~(size_t)255;
        return p;
    };
    u32*   bcur    = (u32*)alloc((size_t)NB * 4);
    int*   rowbeg  = (int*)alloc((size_t)N * 4);
    u16*   deg16   = (u16*)alloc((size_t)N * 2);
    float* dinv    = (float*)alloc((size_t)N * 4);
    int*   csr_s   = (int*)alloc((size_t)NB * CAPB * 4);
    u32*   ebuf    = (u32*)alloc((size_t)NB * CAPB * 4);
    u16*   tileofs = (u16*)alloc((size_t)N * 16 * 2);
    u16*   hs      = (u16*)alloc((size_t)N * 128 * 2);   // row-major [N][128]
    u16*   abf     = (u16*)alloc((size_t)N * 128 * 2);   // row-major [N][128]
    u16*   Wt1     = (u16*)alloc((size_t)128 * KP1 * 2);
    u16*   Wt2     = (u16*)alloc((size_t)128 * KP2 * 2);

    const int nb_gm = (N + 127) / 128;
    const int nb_g  = (N + 15) / 16;

    // ---- W prep (tiny) ----
    k_wprep<<<(128 * KP1 + 255) / 256, 256, 0, stream>>>(W1, Wt1, 400, KP1);
    k_wprep<<<(128 * KP2 + 255) / 256, 256, 0, stream>>>(W2, Wt2, 128, KP2);

    // ---- padded-bucket CSR build (tile-bucketed + tileofs) ----
    k_init_bcur<<<(NB + 255) / 256, 256, 0, stream>>>(bcur, NB);
    k_scatter<<<HB, 256, 0, stream>>>(src, dst, bcur, ebuf, E, NB);
    k_csr_build<<<NB, 256, 0, stream>>>(ebuf, bcur, rowbeg, deg16, dinv, csr_s,
                                        tileofs, N, NB);

    // ---- layer 1 ----
    k_gemm_mfma<0><<<nb_gm, 512, 0, stream>>>(x, Wt1, dinv, hs, N, 400, KP1);
    k_gather<1><<<nb_g, 256, 0, stream>>>(rowbeg, deg16, dinv, csr_s, tileofs,
                                          hs, b1, abf, N, NT);

    // ---- layer 2 ----
    k_gemm_mfma<1><<<nb_gm, 512, 0, stream>>>(abf, Wt2, dinv, hs, N, 128, KP2);
    k_gather<0><<<nb_g, 256, 0, stream>>>(rowbeg, deg16, dinv, csr_s, tileofs,
                                          hs, b2, out, N, NT);
}

// Round 18
// 414.073 us; speedup vs baseline: 1.1918x; 1.1918x over previous
//
#include <hip/hip_runtime.h>

// ---------------------------------------------------------------------------
// 2-layer GCN. Round 18 = round 16 (best: 400 us) + gather inner loop split
// into an unrolled full-chunk path (16 independent H-row loads in flight per
// thread) + tail. Build: padded buckets + per-(node,src-tile) counting sort
// (lists coarse-sorted by src => implicit moving L2 window in gather).
//   hs = bf16(dinv * (A@W)) row-major [N][128]
//   out[d] = relu( dinv[d] * (hs[d] + sum_{s in N(d)} hs[s]) + b )
// ---------------------------------------------------------------------------

#define NBMAX 1024          // max buckets (128 nodes each) -> N <= 131072
#define HB    512           // blocks for the scatter pass
#define CAPB  4608          // slots per bucket (mean 4096 + 8 sigma)
#define TSLOG 13            // src-tile = 8192 nodes = 2 MB of h rows

using u16 = unsigned short;
using u32 = unsigned int;
typedef __attribute__((ext_vector_type(8))) short short8;   // 8 bf16
typedef __attribute__((ext_vector_type(4))) float f32x4;

__device__ __forceinline__ u16 f2bf(float f) {
    u32 u = __float_as_uint(f);
    u += 0x7fffu + ((u >> 16) & 1u);          // round-to-nearest-even
    return (u16)(u >> 16);
}
__device__ __forceinline__ u32 pack2(float a, float b) {
    return (u32)f2bf(a) | ((u32)f2bf(b) << 16);
}
__device__ __forceinline__ float bflo(u32 u) { return __uint_as_float(u << 16); }
__device__ __forceinline__ float bfhi(u32 u) { return __uint_as_float(u & 0xffff0000u); }

// ==================== padded-bucket CSR build (no scan) ====================

__global__ __launch_bounds__(256) void k_init_bcur(u32* bcur, int NB) {
    int b = blockIdx.x * 256 + threadIdx.x;
    if (b < NB) bcur[b] = (u32)b * CAPB;
}

// Scatter edges into bucket-padded ebuf, packed u32 = (dst&127)<<17 | src.
__global__ __launch_bounds__(256) void k_scatter(const int* __restrict__ src,
                                                 const int* __restrict__ dst,
                                                 u32* __restrict__ bcur,
                                                 u32* __restrict__ ebuf,
                                                 int E, int NB) {
    __shared__ u32 hist[NBMAX];
    __shared__ u32 base[NBMAX];
    const int tid = threadIdx.x;
    for (int i = tid; i < NB; i += 256) hist[i] = 0u;
    __syncthreads();
    const int chunk = (E + gridDim.x - 1) / gridDim.x;
    const int e0 = blockIdx.x * chunk;
    const int e1 = min(E, e0 + chunk);
    for (int i = e0 + tid; i < e1; i += 256)
        atomicAdd(&hist[dst[i] >> 7], 1u);
    __syncthreads();
    for (int i = tid; i < NB; i += 256) {
        const u32 c = hist[i];
        base[i] = c ? atomicAdd(&bcur[i], c) : 0u;
    }
    __syncthreads();
    for (int i = tid; i < NB; i += 256) hist[i] = 0u;   // reuse as local cursor
    __syncthreads();
    for (int i = e0 + tid; i < e1; i += 256) {
        const int s = src[i];
        const int d = dst[i];
        const int b = d >> 7;
        const u32 loc = atomicAdd(&hist[b], 1u);
        ebuf[base[b] + loc] = ((u32)(d & 127) << 17) | (u32)s;
    }
}

// One block per bucket: per-(node, src-tile) counting sort -> rowbeg, deg,
// dinv, and tile-bucketed (src-sorted at 8192 granularity) source lists.
__global__ __launch_bounds__(256) void k_csr_build(const u32* __restrict__ ebuf,
                                                   const u32* __restrict__ bcur,
                                                   int* __restrict__ rowbeg,
                                                   u16* __restrict__ deg16,
                                                   float* __restrict__ dinv,
                                                   int* __restrict__ csr_s,
                                                   int N, int NB) {
    __shared__ u32 cnt[2048];      // [node128][tile16]
    __shared__ u32 scan[2048];
    __shared__ u32 cur[2048];
    __shared__ u32 bsum[256];
    const int tid = threadIdx.x;
    const int b = blockIdx.x;
    const int r0 = b * CAPB;
    const int r1 = (int)bcur[b];

    for (int i = tid; i < 2048; i += 256) cnt[i] = 0u;
    __syncthreads();
    for (int i = r0 + tid; i < r1; i += 256) {
        const u32 e = ebuf[i];
        const u32 key = ((e >> 17) << 4) | ((e & 0x1FFFFu) >> TSLOG);
        atomicAdd(&cnt[key], 1u);
    }
    __syncthreads();

    // exclusive scan of cnt[2048]: 8/thread serial + block scan of sums
    const int i8 = tid * 8;
    u32 pre[8];
    u32 run = 0;
#pragma unroll
    for (int j = 0; j < 8; ++j) { pre[j] = run; run += cnt[i8 + j]; }
    bsum[tid] = run;
    __syncthreads();
    for (int off = 1; off < 256; off <<= 1) {
        u32 v = bsum[tid];
        u32 add = (tid >= off) ? bsum[tid - off] : 0u;
        __syncthreads();
        bsum[tid] = v + add;
        __syncthreads();
    }
    const u32 excl = bsum[tid] - run;
#pragma unroll
    for (int j = 0; j < 8; ++j) {
        const u32 x = excl + pre[j];
        scan[i8 + j] = x;
        cur[i8 + j] = x;
    }
    __syncthreads();

    if (tid < 128) {
        const u32 beg  = scan[tid * 16];
        const u32 endv = (tid == 127) ? (u32)(r1 - r0) : scan[(tid + 1) * 16];
        const u32 dg   = endv - beg;
        const int node = b * 128 + tid;
        if (node < N) {
            rowbeg[node] = r0 + (int)beg;
            deg16[node]  = (u16)dg;
            dinv[node]   = rsqrtf((float)(dg + 1u));
        }
    }
    __syncthreads();

    for (int i = r0 + tid; i < r1; i += 256) {
        const u32 e = ebuf[i];
        const u32 sr = e & 0x1FFFFu;
        const u32 key = ((e >> 17) << 4) | (sr >> TSLOG);
        const u32 p = atomicAdd(&cur[key], 1u);
        csr_s[r0 + (int)p] = (int)sr;
    }
}

// ===================== W prep: transpose to [128][KP] bf16 =================
__global__ __launch_bounds__(256) void k_wprep(const float* __restrict__ W,
                                               u16* __restrict__ Wt,
                                               int K, int KP) {
    int idx = blockIdx.x * 256 + threadIdx.x;
    if (idx >= 128 * KP) return;
    int n = idx / KP, k = idx - n * KP;
    Wt[idx] = (k < K) ? f2bf(W[(size_t)k * 128 + n]) : (u16)0;
}

// ========== MFMA GEMM: H[M][128] = bf16(dinv[m] * (A @ W)) row-major =======
// 128x128 tile, 512 threads (8 waves 2x4), wave tile 64x32, BK=64.
// LDS XOR-swizzled on 16B slots. ABF=0: A fp32 [M][K]; ABF=1: A bf16 [M][128].
template <int ABF>
__global__ __launch_bounds__(512) void k_gemm_mfma(
        const void* __restrict__ Aptr,
        const u16* __restrict__ Wt,
        const float* __restrict__ dinv,
        u16* __restrict__ H, int M, int K, int KP) {
    __shared__ u16 smem[16384];        // 32 KB: As | Bs, reused by epilogue
    u16* As = smem;                    // [128][64]
    u16* Bs = smem + 128 * 64;         // [128][64]

    const int tid = threadIdx.x;
    const int row0 = blockIdx.x * 128;
    const int wid = tid >> 6;
    const int lane = tid & 63;
    const int wm = wid >> 2, wn = wid & 3;    // 2 x 4 wave grid
    const int l15 = lane & 15, lg = lane >> 4;
    const int lr7 = l15 & 7;

    const int arow = tid >> 2;                // 0..127 (row for A, col for B)
    const int achk = tid & 3;                 // 16-elem k-chunk
    const int grow = row0 + arow;
    const int ar7 = arow & 7;
    const int s0 = (achk * 2) ^ ar7;          // swizzled 16B slot indices
    const int s1 = (achk * 2 + 1) ^ ar7;

    float4 ar0, ar1, ar2, ar3;                // fp32-A staging
    uint4  au0, au1;                          // bf16-A staging
    uint4  bu0, bu1;                          // W staging

    auto load_tile = [&](int kt) {
        const int k0 = kt * 64 + achk * 16;
        if (ABF) {
            if (grow < M) {
                const u16* ap = (const u16*)Aptr + (size_t)grow * K + k0;
                au0 = *reinterpret_cast<const uint4*>(ap);
                au1 = *reinterpret_cast<const uint4*>(ap + 8);
            } else {
                au0 = make_uint4(0, 0, 0, 0);
                au1 = make_uint4(0, 0, 0, 0);
            }
        } else {
            if (grow < M && k0 < K) {       // K multiple of 16: chunks never straddle
                const float* ap = (const float*)Aptr + (size_t)grow * K + k0;
                ar0 = *reinterpret_cast<const float4*>(ap);
                ar1 = *reinterpret_cast<const float4*>(ap + 4);
                ar2 = *reinterpret_cast<const float4*>(ap + 8);
                ar3 = *reinterpret_cast<const float4*>(ap + 12);
            } else {
                ar0 = ar1 = ar2 = ar3 = make_float4(0.f, 0.f, 0.f, 0.f);
            }
        }
        const u16* wp = Wt + (size_t)arow * KP + k0;    // arow doubles as bcol
        bu0 = *reinterpret_cast<const uint4*>(wp);
        bu1 = *reinterpret_cast<const uint4*>(wp + 8);
    };

    auto store_tile = [&]() {
        uint4 w0, w1;
        if (ABF) {
            w0 = au0; w1 = au1;
        } else {
            w0.x = pack2(ar0.x, ar0.y); w0.y = pack2(ar0.z, ar0.w);
            w0.z = pack2(ar1.x, ar1.y); w0.w = pack2(ar1.z, ar1.w);
            w1.x = pack2(ar2.x, ar2.y); w1.y = pack2(ar2.z, ar2.w);
            w1.z = pack2(ar3.x, ar3.y); w1.w = pack2(ar3.z, ar3.w);
        }
        u16* ad = As + arow * 64;
        *reinterpret_cast<uint4*>(ad + s0 * 8) = w0;
        *reinterpret_cast<uint4*>(ad + s1 * 8) = w1;
        u16* bd = Bs + arow * 64;
        *reinterpret_cast<uint4*>(bd + s0 * 8) = bu0;
        *reinterpret_cast<uint4*>(bd + s1 * 8) = bu1;
    };

    f32x4 acc[4][2];
#pragma unroll
    for (int i = 0; i < 4; ++i)
#pragma unroll
        for (int j = 0; j < 2; ++j)
            acc[i][j] = (f32x4){0.f, 0.f, 0.f, 0.f};

    const int NT = KP >> 6;
    load_tile(0);
    for (int kt = 0; kt < NT; ++kt) {
        __syncthreads();
        store_tile();
        __syncthreads();
        if (kt + 1 < NT) load_tile(kt + 1);   // reg prefetch under MFMA
#pragma unroll
        for (int sub = 0; sub < 2; ++sub) {
            const int slot = ((sub * 4 + lg) ^ lr7) * 8;
            short8 af[4], bf[2];
#pragma unroll
            for (int i = 0; i < 4; ++i)
                af[i] = *reinterpret_cast<const short8*>(
                    As + (wm * 64 + i * 16 + l15) * 64 + slot);
#pragma unroll
            for (int j = 0; j < 2; ++j)
                bf[j] = *reinterpret_cast<const short8*>(
                    Bs + (wn * 32 + j * 16 + l15) * 64 + slot);
#pragma unroll
            for (int i = 0; i < 4; ++i)
#pragma unroll
                for (int j = 0; j < 2; ++j)
                    acc[i][j] = __builtin_amdgcn_mfma_f32_16x16x32_bf16(
                        af[i], bf[j], acc[i][j], 0, 0, 0);
        }
    }

    // Epilogue: dinv*acc -> bf16 staged in LDS (CSTR=136) -> 32B row stores.
    const int CSTR = 136;
    __syncthreads();
#pragma unroll
    for (int half = 0; half < 2; ++half) {
        if (wm == half) {
#pragma unroll
            for (int i = 0; i < 4; ++i)
#pragma unroll
                for (int r = 0; r < 4; ++r) {
                    const int gr = row0 + half * 64 + i * 16 + lg * 4 + r;
                    const float dv = (gr < M) ? dinv[gr] : 0.f;
#pragma unroll
                    for (int j = 0; j < 2; ++j)
                        smem[(i * 16 + lg * 4 + r) * CSTR + wn * 32 + j * 16 + l15] =
                            f2bf(acc[i][j][r] * dv);
                }
        }
        __syncthreads();
        {
            const int rr = tid >> 3;            // 0..63
            const int cc = (tid & 7) * 16;      // 0..112
            const int gr = row0 + half * 64 + rr;
            if (gr < M) {
                const u16* cp = smem + rr * CSTR + cc;
                uint4 q0 = *reinterpret_cast<const uint4*>(cp);
                uint4 q1 = *reinterpret_cast<const uint4*>(cp + 8);
                uint4* hp = reinterpret_cast<uint4*>(H + (size_t)gr * 128 + cc);
                hp[0] = q0; hp[1] = q1;
            }
        }
        __syncthreads();
    }
}

// ========================= gather (pull aggregation) =======================
// 16 nodes/block, 16 lanes/node, 8 bf16 cols (16B) per lane. Lists are
// coarse-sorted by src (tile-bucketed) => implicit moving window.
// Inner loop split: unrolled full-chunk path (16 independent row loads in
// flight per thread) + runtime-count tail.
template <int OUTBF>
__global__ __launch_bounds__(256) void k_gather(const int* __restrict__ rowbeg,
                                                const u16* __restrict__ deg16,
                                                const float* __restrict__ dinv,
                                                const int* __restrict__ csr_s,
                                                const u16* __restrict__ H,
                                                const float* __restrict__ bias,
                                                void* __restrict__ outp, int N) {
    const int t = threadIdx.x;
    const int node = blockIdx.x * 16 + (t >> 4);
    if (node >= N) return;
    const int lane = t & 15;
    const int c8 = lane * 8;

    const uint4 hv = *reinterpret_cast<const uint4*>(H + (size_t)node * 128 + c8);
    float acc0 = bflo(hv.x), acc1 = bfhi(hv.x);
    float acc2 = bflo(hv.y), acc3 = bfhi(hv.y);
    float acc4 = bflo(hv.z), acc5 = bfhi(hv.z);
    float acc6 = bflo(hv.w), acc7 = bfhi(hv.w);

    const int beg = rowbeg[node];
    const int end = beg + (int)deg16[node];
    int r = beg;

    // Full 16-wide chunks: unrolled, 16 independent H-row loads in flight.
    for (; r + 16 <= end; r += 16) {
        const int sv = csr_s[r + lane];
        uint4 x[16];
#pragma unroll
        for (int j = 0; j < 16; ++j) {
            const int s = __shfl(sv, j, 16);
            x[j] = *reinterpret_cast<const uint4*>(H + (size_t)s * 128 + c8);
        }
#pragma unroll
        for (int j = 0; j < 16; ++j) {
            acc0 += bflo(x[j].x); acc1 += bfhi(x[j].x);
            acc2 += bflo(x[j].y); acc3 += bfhi(x[j].y);
            acc4 += bflo(x[j].z); acc5 += bfhi(x[j].z);
            acc6 += bflo(x[j].w); acc7 += bfhi(x[j].w);
        }
    }
    // Tail.
    if (r < end) {
        const int cntc = end - r;
        const int sv = (lane < cntc) ? csr_s[r + lane] : 0;
        for (int j = 0; j < cntc; ++j) {
            const int s = __shfl(sv, j, 16);
            const uint4 x = *reinterpret_cast<const uint4*>(H + (size_t)s * 128 + c8);
            acc0 += bflo(x.x); acc1 += bfhi(x.x);
            acc2 += bflo(x.y); acc3 += bfhi(x.y);
            acc4 += bflo(x.z); acc5 += bfhi(x.z);
            acc6 += bflo(x.w); acc7 += bfhi(x.w);
        }
    }

    const float dv = dinv[node];
    const float4 b0 = *reinterpret_cast<const float4*>(bias + c8);
    const float4 b1 = *reinterpret_cast<const float4*>(bias + c8 + 4);
    const float r0 = fmaxf(fmaf(acc0, dv, b0.x), 0.f);
    const float r1 = fmaxf(fmaf(acc1, dv, b0.y), 0.f);
    const float r2 = fmaxf(fmaf(acc2, dv, b0.z), 0.f);
    const float r3 = fmaxf(fmaf(acc3, dv, b0.w), 0.f);
    const float r4 = fmaxf(fmaf(acc4, dv, b1.x), 0.f);
    const float r5 = fmaxf(fmaf(acc5, dv, b1.y), 0.f);
    const float r6 = fmaxf(fmaf(acc6, dv, b1.z), 0.f);
    const float r7 = fmaxf(fmaf(acc7, dv, b1.w), 0.f);

    if (OUTBF) {
        uint4 q;
        q.x = pack2(r0, r1); q.y = pack2(r2, r3);
        q.z = pack2(r4, r5); q.w = pack2(r6, r7);
        u16* op = (u16*)outp + (size_t)node * 128 + c8;
        *reinterpret_cast<uint4*>(op) = q;
    } else {
        float* op = (float*)outp + (size_t)node * 128 + c8;
        *reinterpret_cast<float4*>(op)     = make_float4(r0, r1, r2, r3);
        *reinterpret_cast<float4*>(op + 4) = make_float4(r4, r5, r6, r7);
    }
}

// ===========================================================================

extern "C" void kernel_launch(void* const* d_in, const int* in_sizes, int n_in,
                              void* d_out, int out_size, void* d_ws, size_t ws_size,
                              hipStream_t stream) {
    const float* x  = (const float*)d_in[0];
    const int*   ei = (const int*)d_in[1];
    const float* W1 = (const float*)d_in[3];
    const float* b1 = (const float*)d_in[4];
    const float* W2 = (const float*)d_in[5];
    const float* b2 = (const float*)d_in[6];
    float* out = (float*)d_out;

    const int N = in_sizes[0] / 400;
    const int E = in_sizes[1] / 2;
    const int* src = ei;
    const int* dst = ei + E;
    const int NB = (N + 127) >> 7;
    const int KP1 = 448;                // 400 padded to 7*64
    const int KP2 = 128;

    char* ws = (char*)d_ws;
    size_t off = 0;
    auto alloc = [&](size_t bytes) {
        void* p = ws + off;
        off = (off + bytes + 255) & ~(size_t)255;
        return p;
    };
    u32*   bcur   = (u32*)alloc((size_t)NB * 4);
    int*   rowbeg = (int*)alloc((size_t)N * 4);
    u16*   deg16  = (u16*)alloc((size_t)N * 2);
    float* dinv   = (float*)alloc((size_t)N * 4);
    int*   csr_s  = (int*)alloc((size_t)NB * CAPB * 4);
    u32*   ebuf   = (u32*)alloc((size_t)NB * CAPB * 4);
    u16*   hs     = (u16*)alloc((size_t)N * 128 * 2);   // row-major [N][128]
    u16*   abf    = (u16*)alloc((size_t)N * 128 * 2);   // row-major [N][128]
    u16*   Wt1    = (u16*)alloc((size_t)128 * KP1 * 2);
    u16*   Wt2    = (u16*)alloc((size_t)128 * KP2 * 2);

    const int nb_gm = (N + 127) / 128;
    const int nb_g  = (N + 15) / 16;

    // ---- W prep (tiny) ----
    k_wprep<<<(128 * KP1 + 255) / 256, 256, 0, stream>>>(W1, Wt1, 400, KP1);
    k_wprep<<<(128 * KP2 + 255) / 256, 256, 0, stream>>>(W2, Wt2, 128, KP2);

    // ---- padded-bucket CSR build (tile-bucketed = coarse src-sorted) ----
    k_init_bcur<<<(NB + 255) / 256, 256, 0, stream>>>(bcur, NB);
    k_scatter<<<HB, 256, 0, stream>>>(src, dst, bcur, ebuf, E, NB);
    k_csr_build<<<NB, 256, 0, stream>>>(ebuf, bcur, rowbeg, deg16, dinv, csr_s, N, NB);

    // ---- layer 1 ----
    k_gemm_mfma<0><<<nb_gm, 512, 0, stream>>>(x, Wt1, dinv, hs, N, 400, KP1);
    k_gather<1><<<nb_g, 256, 0, stream>>>(rowbeg, deg16, dinv, csr_s, hs, b1, abf, N);

    // ---- layer 2 ----
    k_gemm_mfma<1><<<nb_gm, 512, 0, stream>>>(abf, Wt2, dinv, hs, N, 128, KP2);
    k_gather<0><<<nb_g, 256, 0, stream>>>(rowbeg, deg16, dinv, csr_s, hs, b2, out, N);
}

// Round 19
// 399.744 us; speedup vs baseline: 1.2345x; 1.0358x over previous
//
#include <hip/hip_runtime.h>

// ---------------------------------------------------------------------------
// 2-layer GCN. Round 19 = exact revert to round 16 (best measured: 400 us).
// Build: padded buckets + per-(node,src-tile) counting sort (lists coarse-
// sorted by src => implicit moving L2 window in the free-running gather).
// Gather: plain chunked pull (round-13 form, 20 VGPR, ~72% occupancy).
//   hs = bf16(dinv * (A@W)) row-major [N][128]
//   out[d] = relu( dinv[d] * (hs[d] + sum_{s in N(d)} hs[s]) + b )
// ---------------------------------------------------------------------------

#define NBMAX 1024          // max buckets (128 nodes each) -> N <= 131072
#define HB    512           // blocks for the scatter pass
#define CAPB  4608          // slots per bucket (mean 4096 + 8 sigma)
#define TSLOG 13            // src-tile = 8192 nodes = 2 MB of h rows

using u16 = unsigned short;
using u32 = unsigned int;
typedef __attribute__((ext_vector_type(8))) short short8;   // 8 bf16
typedef __attribute__((ext_vector_type(4))) float f32x4;

__device__ __forceinline__ u16 f2bf(float f) {
    u32 u = __float_as_uint(f);
    u += 0x7fffu + ((u >> 16) & 1u);          // round-to-nearest-even
    return (u16)(u >> 16);
}
__device__ __forceinline__ u32 pack2(float a, float b) {
    return (u32)f2bf(a) | ((u32)f2bf(b) << 16);
}
__device__ __forceinline__ float bflo(u32 u) { return __uint_as_float(u << 16); }
__device__ __forceinline__ float bfhi(u32 u) { return __uint_as_float(u & 0xffff0000u); }

// ==================== padded-bucket CSR build (no scan) ====================

__global__ __launch_bounds__(256) void k_init_bcur(u32* bcur, int NB) {
    int b = blockIdx.x * 256 + threadIdx.x;
    if (b < NB) bcur[b] = (u32)b * CAPB;
}

// Scatter edges into bucket-padded ebuf, packed u32 = (dst&127)<<17 | src.
__global__ __launch_bounds__(256) void k_scatter(const int* __restrict__ src,
                                                 const int* __restrict__ dst,
                                                 u32* __restrict__ bcur,
                                                 u32* __restrict__ ebuf,
                                                 int E, int NB) {
    __shared__ u32 hist[NBMAX];
    __shared__ u32 base[NBMAX];
    const int tid = threadIdx.x;
    for (int i = tid; i < NB; i += 256) hist[i] = 0u;
    __syncthreads();
    const int chunk = (E + gridDim.x - 1) / gridDim.x;
    const int e0 = blockIdx.x * chunk;
    const int e1 = min(E, e0 + chunk);
    for (int i = e0 + tid; i < e1; i += 256)
        atomicAdd(&hist[dst[i] >> 7], 1u);
    __syncthreads();
    for (int i = tid; i < NB; i += 256) {
        const u32 c = hist[i];
        base[i] = c ? atomicAdd(&bcur[i], c) : 0u;
    }
    __syncthreads();
    for (int i = tid; i < NB; i += 256) hist[i] = 0u;   // reuse as local cursor
    __syncthreads();
    for (int i = e0 + tid; i < e1; i += 256) {
        const int s = src[i];
        const int d = dst[i];
        const int b = d >> 7;
        const u32 loc = atomicAdd(&hist[b], 1u);
        ebuf[base[b] + loc] = ((u32)(d & 127) << 17) | (u32)s;
    }
}

// One block per bucket: per-(node, src-tile) counting sort -> rowbeg, deg,
// dinv, and tile-bucketed (src-sorted at 8192 granularity) source lists.
__global__ __launch_bounds__(256) void k_csr_build(const u32* __restrict__ ebuf,
                                                   const u32* __restrict__ bcur,
                                                   int* __restrict__ rowbeg,
                                                   u16* __restrict__ deg16,
                                                   float* __restrict__ dinv,
                                                   int* __restrict__ csr_s,
                                                   int N, int NB) {
    __shared__ u32 cnt[2048];      // [node128][tile16]
    __shared__ u32 scan[2048];
    __shared__ u32 cur[2048];
    __shared__ u32 bsum[256];
    const int tid = threadIdx.x;
    const int b = blockIdx.x;
    const int r0 = b * CAPB;
    const int r1 = (int)bcur[b];

    for (int i = tid; i < 2048; i += 256) cnt[i] = 0u;
    __syncthreads();
    for (int i = r0 + tid; i < r1; i += 256) {
        const u32 e = ebuf[i];
        const u32 key = ((e >> 17) << 4) | ((e & 0x1FFFFu) >> TSLOG);
        atomicAdd(&cnt[key], 1u);
    }
    __syncthreads();

    // exclusive scan of cnt[2048]: 8/thread serial + block scan of sums
    const int i8 = tid * 8;
    u32 pre[8];
    u32 run = 0;
#pragma unroll
    for (int j = 0; j < 8; ++j) { pre[j] = run; run += cnt[i8 + j]; }
    bsum[tid] = run;
    __syncthreads();
    for (int off = 1; off < 256; off <<= 1) {
        u32 v = bsum[tid];
        u32 add = (tid >= off) ? bsum[tid - off] : 0u;
        __syncthreads();
        bsum[tid] = v + add;
        __syncthreads();
    }
    const u32 excl = bsum[tid] - run;
#pragma unroll
    for (int j = 0; j < 8; ++j) {
        const u32 x = excl + pre[j];
        scan[i8 + j] = x;
        cur[i8 + j] = x;
    }
    __syncthreads();

    if (tid < 128) {
        const u32 beg  = scan[tid * 16];
        const u32 endv = (tid == 127) ? (u32)(r1 - r0) : scan[(tid + 1) * 16];
        const u32 dg   = endv - beg;
        const int node = b * 128 + tid;
        if (node < N) {
            rowbeg[node] = r0 + (int)beg;
            deg16[node]  = (u16)dg;
            dinv[node]   = rsqrtf((float)(dg + 1u));
        }
    }
    __syncthreads();

    for (int i = r0 + tid; i < r1; i += 256) {
        const u32 e = ebuf[i];
        const u32 sr = e & 0x1FFFFu;
        const u32 key = ((e >> 17) << 4) | (sr >> TSLOG);
        const u32 p = atomicAdd(&cur[key], 1u);
        csr_s[r0 + (int)p] = (int)sr;
    }
}

// ===================== W prep: transpose to [128][KP] bf16 =================
__global__ __launch_bounds__(256) void k_wprep(const float* __restrict__ W,
                                               u16* __restrict__ Wt,
                                               int K, int KP) {
    int idx = blockIdx.x * 256 + threadIdx.x;
    if (idx >= 128 * KP) return;
    int n = idx / KP, k = idx - n * KP;
    Wt[idx] = (k < K) ? f2bf(W[(size_t)k * 128 + n]) : (u16)0;
}

// ========== MFMA GEMM: H[M][128] = bf16(dinv[m] * (A @ W)) row-major =======
// 128x128 tile, 512 threads (8 waves 2x4), wave tile 64x32, BK=64.
// LDS XOR-swizzled on 16B slots. ABF=0: A fp32 [M][K]; ABF=1: A bf16 [M][128].
template <int ABF>
__global__ __launch_bounds__(512) void k_gemm_mfma(
        const void* __restrict__ Aptr,
        const u16* __restrict__ Wt,
        const float* __restrict__ dinv,
        u16* __restrict__ H, int M, int K, int KP) {
    __shared__ u16 smem[16384];        // 32 KB: As | Bs, reused by epilogue
    u16* As = smem;                    // [128][64]
    u16* Bs = smem + 128 * 64;         // [128][64]

    const int tid = threadIdx.x;
    const int row0 = blockIdx.x * 128;
    const int wid = tid >> 6;
    const int lane = tid & 63;
    const int wm = wid >> 2, wn = wid & 3;    // 2 x 4 wave grid
    const int l15 = lane & 15, lg = lane >> 4;
    const int lr7 = l15 & 7;

    const int arow = tid >> 2;                // 0..127 (row for A, col for B)
    const int achk = tid & 3;                 // 16-elem k-chunk
    const int grow = row0 + arow;
    const int ar7 = arow & 7;
    const int s0 = (achk * 2) ^ ar7;          // swizzled 16B slot indices
    const int s1 = (achk * 2 + 1) ^ ar7;

    float4 ar0, ar1, ar2, ar3;                // fp32-A staging
    uint4  au0, au1;                          // bf16-A staging
    uint4  bu0, bu1;                          // W staging

    auto load_tile = [&](int kt) {
        const int k0 = kt * 64 + achk * 16;
        if (ABF) {
            if (grow < M) {
                const u16* ap = (const u16*)Aptr + (size_t)grow * K + k0;
                au0 = *reinterpret_cast<const uint4*>(ap);
                au1 = *reinterpret_cast<const uint4*>(ap + 8);
            } else {
                au0 = make_uint4(0, 0, 0, 0);
                au1 = make_uint4(0, 0, 0, 0);
            }
        } else {
            if (grow < M && k0 < K) {       // K multiple of 16: chunks never straddle
                const float* ap = (const float*)Aptr + (size_t)grow * K + k0;
                ar0 = *reinterpret_cast<const float4*>(ap);
                ar1 = *reinterpret_cast<const float4*>(ap + 4);
                ar2 = *reinterpret_cast<const float4*>(ap + 8);
                ar3 = *reinterpret_cast<const float4*>(ap + 12);
            } else {
                ar0 = ar1 = ar2 = ar3 = make_float4(0.f, 0.f, 0.f, 0.f);
            }
        }
        const u16* wp = Wt + (size_t)arow * KP + k0;    // arow doubles as bcol
        bu0 = *reinterpret_cast<const uint4*>(wp);
        bu1 = *reinterpret_cast<const uint4*>(wp + 8);
    };

    auto store_tile = [&]() {
        uint4 w0, w1;
        if (ABF) {
            w0 = au0; w1 = au1;
        } else {
            w0.x = pack2(ar0.x, ar0.y); w0.y = pack2(ar0.z, ar0.w);
            w0.z = pack2(ar1.x, ar1.y); w0.w = pack2(ar1.z, ar1.w);
            w1.x = pack2(ar2.x, ar2.y); w1.y = pack2(ar2.z, ar2.w);
            w1.z = pack2(ar3.x, ar3.y); w1.w = pack2(ar3.z, ar3.w);
        }
        u16* ad = As + arow * 64;
        *reinterpret_cast<uint4*>(ad + s0 * 8) = w0;
        *reinterpret_cast<uint4*>(ad + s1 * 8) = w1;
        u16* bd = Bs + arow * 64;
        *reinterpret_cast<uint4*>(bd + s0 * 8) = bu0;
        *reinterpret_cast<uint4*>(bd + s1 * 8) = bu1;
    };

    f32x4 acc[4][2];
#pragma unroll
    for (int i = 0; i < 4; ++i)
#pragma unroll
        for (int j = 0; j < 2; ++j)
            acc[i][j] = (f32x4){0.f, 0.f, 0.f, 0.f};

    const int NT = KP >> 6;
    load_tile(0);
    for (int kt = 0; kt < NT; ++kt) {
        __syncthreads();
        store_tile();
        __syncthreads();
        if (kt + 1 < NT) load_tile(kt + 1);   // reg prefetch under MFMA
#pragma unroll
        for (int sub = 0; sub < 2; ++sub) {
            const int slot = ((sub * 4 + lg) ^ lr7) * 8;
            short8 af[4], bf[2];
#pragma unroll
            for (int i = 0; i < 4; ++i)
                af[i] = *reinterpret_cast<const short8*>(
                    As + (wm * 64 + i * 16 + l15) * 64 + slot);
#pragma unroll
            for (int j = 0; j < 2; ++j)
                bf[j] = *reinterpret_cast<const short8*>(
                    Bs + (wn * 32 + j * 16 + l15) * 64 + slot);
#pragma unroll
            for (int i = 0; i < 4; ++i)
#pragma unroll
                for (int j = 0; j < 2; ++j)
                    acc[i][j] = __builtin_amdgcn_mfma_f32_16x16x32_bf16(
                        af[i], bf[j], acc[i][j], 0, 0, 0);
        }
    }

    // Epilogue: dinv*acc -> bf16 staged in LDS (CSTR=136) -> 32B row stores.
    const int CSTR = 136;
    __syncthreads();
#pragma unroll
    for (int half = 0; half < 2; ++half) {
        if (wm == half) {
#pragma unroll
            for (int i = 0; i < 4; ++i)
#pragma unroll
                for (int r = 0; r < 4; ++r) {
                    const int gr = row0 + half * 64 + i * 16 + lg * 4 + r;
                    const float dv = (gr < M) ? dinv[gr] : 0.f;
#pragma unroll
                    for (int j = 0; j < 2; ++j)
                        smem[(i * 16 + lg * 4 + r) * CSTR + wn * 32 + j * 16 + l15] =
                            f2bf(acc[i][j][r] * dv);
                }
        }
        __syncthreads();
        {
            const int rr = tid >> 3;            // 0..63
            const int cc = (tid & 7) * 16;      // 0..112
            const int gr = row0 + half * 64 + rr;
            if (gr < M) {
                const u16* cp = smem + rr * CSTR + cc;
                uint4 q0 = *reinterpret_cast<const uint4*>(cp);
                uint4 q1 = *reinterpret_cast<const uint4*>(cp + 8);
                uint4* hp = reinterpret_cast<uint4*>(H + (size_t)gr * 128 + cc);
                hp[0] = q0; hp[1] = q1;
            }
        }
        __syncthreads();
    }
}

// ========================= gather (pull aggregation) =======================
// Round-13/16 form: 16 nodes/block, 16 lanes/node, 8 bf16 cols (16B) per
// lane. Lists coarse-sorted by src (tile-bucketed) => implicit moving window.
template <int OUTBF>
__global__ __launch_bounds__(256) void k_gather(const int* __restrict__ rowbeg,
                                                const u16* __restrict__ deg16,
                                                const float* __restrict__ dinv,
                                                const int* __restrict__ csr_s,
                                                const u16* __restrict__ H,
                                                const float* __restrict__ bias,
                                                void* __restrict__ outp, int N) {
    const int t = threadIdx.x;
    const int node = blockIdx.x * 16 + (t >> 4);
    if (node >= N) return;
    const int lane = t & 15;
    const int c8 = lane * 8;

    const uint4 hv = *reinterpret_cast<const uint4*>(H + (size_t)node * 128 + c8);
    float acc0 = bflo(hv.x), acc1 = bfhi(hv.x);
    float acc2 = bflo(hv.y), acc3 = bfhi(hv.y);
    float acc4 = bflo(hv.z), acc5 = bfhi(hv.z);
    float acc6 = bflo(hv.w), acc7 = bfhi(hv.w);

    const int beg = rowbeg[node];
    const int end = beg + (int)deg16[node];
    for (int r = beg; r < end; r += 16) {
        const int cntc = min(16, end - r);
        int sv = (lane < cntc) ? csr_s[r + lane] : 0;
        for (int j = 0; j < cntc; ++j) {
            const int s = __shfl(sv, j, 16);
            const uint4 x = *reinterpret_cast<const uint4*>(H + (size_t)s * 128 + c8);
            acc0 += bflo(x.x); acc1 += bfhi(x.x);
            acc2 += bflo(x.y); acc3 += bfhi(x.y);
            acc4 += bflo(x.z); acc5 += bfhi(x.z);
            acc6 += bflo(x.w); acc7 += bfhi(x.w);
        }
    }

    const float dv = dinv[node];
    const float4 b0 = *reinterpret_cast<const float4*>(bias + c8);
    const float4 b1 = *reinterpret_cast<const float4*>(bias + c8 + 4);
    const float r0 = fmaxf(fmaf(acc0, dv, b0.x), 0.f);
    const float r1 = fmaxf(fmaf(acc1, dv, b0.y), 0.f);
    const float r2 = fmaxf(fmaf(acc2, dv, b0.z), 0.f);
    const float r3 = fmaxf(fmaf(acc3, dv, b0.w), 0.f);
    const float r4 = fmaxf(fmaf(acc4, dv, b1.x), 0.f);
    const float r5 = fmaxf(fmaf(acc5, dv, b1.y), 0.f);
    const float r6 = fmaxf(fmaf(acc6, dv, b1.z), 0.f);
    const float r7 = fmaxf(fmaf(acc7, dv, b1.w), 0.f);

    if (OUTBF) {
        uint4 q;
        q.x = pack2(r0, r1); q.y = pack2(r2, r3);
        q.z = pack2(r4, r5); q.w = pack2(r6, r7);
        u16* op = (u16*)outp + (size_t)node * 128 + c8;
        *reinterpret_cast<uint4*>(op) = q;
    } else {
        float* op = (float*)outp + (size_t)node * 128 + c8;
        *reinterpret_cast<float4*>(op)     = make_float4(r0, r1, r2, r3);
        *reinterpret_cast<float4*>(op + 4) = make_float4(r4, r5, r6, r7);
    }
}

// ===========================================================================

extern "C" void kernel_launch(void* const* d_in, const int* in_sizes, int n_in,
                              void* d_out, int out_size, void* d_ws, size_t ws_size,
                              hipStream_t stream) {
    const float* x  = (const float*)d_in[0];
    const int*   ei = (const int*)d_in[1];
    const float* W1 = (const float*)d_in[3];
    const float* b1 = (const float*)d_in[4];
    const float* W2 = (const float*)d_in[5];
    const float* b2 = (const float*)d_in[6];
    float* out = (float*)d_out;

    const int N = in_sizes[0] / 400;
    const int E = in_sizes[1] / 2;
    const int* src = ei;
    const int* dst = ei + E;
    const int NB = (N + 127) >> 7;
    const int KP1 = 448;                // 400 padded to 7*64
    const int KP2 = 128;

    char* ws = (char*)d_ws;
    size_t off = 0;
    auto alloc = [&](size_t bytes) {
        void* p = ws + off;
        off = (off + bytes + 255) & ~(size_t)255;
        return p;
    };
    u32*   bcur   = (u32*)alloc((size_t)NB * 4);
    int*   rowbeg = (int*)alloc((size_t)N * 4);
    u16*   deg16  = (u16*)alloc((size_t)N * 2);
    float* dinv   = (float*)alloc((size_t)N * 4);
    int*   csr_s  = (int*)alloc((size_t)NB * CAPB * 4);
    u32*   ebuf   = (u32*)alloc((size_t)NB * CAPB * 4);
    u16*   hs     = (u16*)alloc((size_t)N * 128 * 2);   // row-major [N][128]
    u16*   abf    = (u16*)alloc((size_t)N * 128 * 2);   // row-major [N][128]
    u16*   Wt1    = (u16*)alloc((size_t)128 * KP1 * 2);
    u16*   Wt2    = (u16*)alloc((size_t)128 * KP2 * 2);

    const int nb_gm = (N + 127) / 128;
    const int nb_g  = (N + 15) / 16;

    // ---- W prep (tiny) ----
    k_wprep<<<(128 * KP1 + 255) / 256, 256, 0, stream>>>(W1, Wt1, 400, KP1);
    k_wprep<<<(128 * KP2 + 255) / 256, 256, 0, stream>>>(W2, Wt2, 128, KP2);

    // ---- padded-bucket CSR build (tile-bucketed = coarse src-sorted) ----
    k_init_bcur<<<(NB + 255) / 256, 256, 0, stream>>>(bcur, NB);
    k_scatter<<<HB, 256, 0, stream>>>(src, dst, bcur, ebuf, E, NB);
    k_csr_build<<<NB, 256, 0, stream>>>(ebuf, bcur, rowbeg, deg16, dinv, csr_s, N, NB);

    // ---- layer 1 ----
    k_gemm_mfma<0><<<nb_gm, 512, 0, stream>>>(x, Wt1, dinv, hs, N, 400, KP1);
    k_gather<1><<<nb_g, 256, 0, stream>>>(rowbeg, deg16, dinv, csr_s, hs, b1, abf, N);

    // ---- layer 2 ----
    k_gemm_mfma<1><<<nb_gm, 512, 0, stream>>>(abf, Wt2, dinv, hs, N, 128, KP2);
    k_gather<0><<<nb_g, 256, 0, stream>>>(rowbeg, deg16, dinv, csr_s, hs, b2, out, N);
}